// Round 4
// baseline (297.714 us; speedup 1.0000x reference)
//
#include <hip/hip_runtime.h>
#include <cstdint>
#include <cstddef>

#define D_MODEL 2048
#define SEQ 2048
#define BATCH 2
#define HEADS 16
#define DH 128
#define MROWS (BATCH * SEQ) /* 4096 */

typedef __attribute__((ext_vector_type(8))) short short8;
typedef __attribute__((ext_vector_type(4))) float f32x4;
typedef __attribute__((ext_vector_type(16))) float f32x16;
typedef __attribute__((ext_vector_type(2))) unsigned int uint2e;

__device__ __forceinline__ unsigned short f2bf(float f) {
    unsigned int u = __builtin_bit_cast(unsigned int, f);
    u += 0x7fffu + ((u >> 16) & 1u);   // round-to-nearest-even
    return (unsigned short)(u >> 16);
}

__device__ __forceinline__ unsigned int cvt_pk_bf16(float lo, float hi) {
    unsigned int w;
    asm("v_cvt_pk_bf16_f32 %0, %1, %2" : "=v"(w) : "v"(lo), "v"(hi));
    return w;
}

__device__ __forceinline__ void swap32(unsigned int& x, unsigned int& y) {
#if __has_builtin(__builtin_amdgcn_permlane32_swap)
    uint2e r = __builtin_amdgcn_permlane32_swap(x, y, false, false);
    x = r[0]; y = r[1];
#else
    const int hi = (threadIdx.x >> 5) & 1;
    const unsigned int gx = (unsigned int)__shfl_xor((int)x, 32);
    const unsigned int gy = (unsigned int)__shfl_xor((int)y, 32);
    const unsigned int nx = hi ? gy : x;
    const unsigned int ny = hi ? y : gx;
    x = nx; y = ny;
#endif
}

__device__ __forceinline__ void gload_lds16(const unsigned short* g, unsigned short* l) {
    __builtin_amdgcn_global_load_lds(
        (const __attribute__((address_space(1))) void*)g,
        (__attribute__((address_space(3))) void*)l, 16, 0, 0);
}

// ---------------- fp32 -> bf16 conversion ----------------
__global__ __launch_bounds__(256) void cvt_kernel(const float* __restrict__ in,
                                                  unsigned short* __restrict__ out, int n4) {
    int i = blockIdx.x * 256 + threadIdx.x;
    if (i < n4) {
        const float4 v = reinterpret_cast<const float4*>(in)[i];
        ushort4 o;
        o.x = f2bf(v.x); o.y = f2bf(v.y); o.z = f2bf(v.z); o.w = f2bf(v.w);
        reinterpret_cast<ushort4*>(out)[i] = o;
    }
}

// fused conversion of the 4 weight matrices (outputs contiguous in ws)
__global__ __launch_bounds__(256) void cvt4_kernel(const float* __restrict__ w0,
                                                   const float* __restrict__ w1,
                                                   const float* __restrict__ w2,
                                                   const float* __restrict__ w3,
                                                   unsigned short* __restrict__ out) {
    const int per = (D_MODEL * D_MODEL) / 4;  // float4s per weight
    int i = blockIdx.x * 256 + threadIdx.x;
    const int sel = i / per;
    const int off = i - sel * per;
    const float* s = sel == 0 ? w0 : sel == 1 ? w1 : sel == 2 ? w2 : w3;
    const float4 v = reinterpret_cast<const float4*>(s)[off];
    ushort4 o;
    o.x = f2bf(v.x); o.y = f2bf(v.y); o.z = f2bf(v.z); o.w = f2bf(v.w);
    reinterpret_cast<ushort4*>(out)[i] = o;
}

// ---------------- pipelined GEMM: C = A * W^T + bias ----------------
// BM=256, BN=128, BK=32; 8 waves (4M x 2N, 64x64/wave); 48KB LDS dbuf;
// raw s_barrier + counted vmcnt(3) (tile t+2 issued at tile-t end -> tile t+1's
// loads get a full tile of latency coverage; never drained mid-loop).
// MODE 0: fused QKV (N=6144 over 3 weights; V written transposed).
// MODE 1: f32 row-major out (attention output projection).
template <int MODE>
__global__ __launch_bounds__(512, 4)
void gemm8(const unsigned short* __restrict__ A,
           const unsigned short* __restrict__ W0,
           const unsigned short* __restrict__ W1,
           const unsigned short* __restrict__ W2,
           const float* __restrict__ b0f,
           const float* __restrict__ b1f,
           const float* __restrict__ b2f,
           unsigned short* __restrict__ O0,
           unsigned short* __restrict__ O1,
           unsigned short* __restrict__ O2,
           float* __restrict__ OF) {
    constexpr int BM = 256, BN = 128, BK = 32;
    constexpr int K = D_MODEL;
    constexpr int NTILES = K / BK;                               // 64
    constexpr int NT_N = (MODE == 0 ? (3 * D_MODEL) / BN : D_MODEL / BN);
    __shared__ unsigned short As[2][BM * BK];                    // 2 x 16KB
    __shared__ unsigned short Bs[2][BN * BK];                    // 2 x 8KB

    const int tid  = threadIdx.x;
    const int lane = tid & 63;
    const int wid  = tid >> 6;

    // T1: bijective XCD-chunk swizzle; nt-fastest so consecutive work shares A panel
    constexpr int NWG = (MROWS / BM) * NT_N;                     // 768 or 256
    const int wk = (blockIdx.x & 7) * (NWG >> 3) + (blockIdx.x >> 3);
    const int nt = wk % NT_N;
    const int mt = wk / NT_N;
    const int m0 = mt * BM;
    const int n0 = nt * BN;

    const unsigned short* Bw;
    const float* bias;
    int nloc;
    if constexpr (MODE == 0) {
        const int nsel = n0 >> 11;
        nloc = n0 & 2047;
        Bw = nsel == 0 ? W0 : (nsel == 1 ? W1 : W2);
        bias = nsel == 0 ? b0f : (nsel == 1 ? b1f : b2f);
    } else {
        Bw = W0; bias = b0f; nloc = n0;
    }

    // staging: wave covers 16 rows x 4 chunks (16B) per load; inverse-swizzled source
    const int srow = lane >> 2;           // row within wave's 16-row strip
    const int schk = lane & 3;
    const int r0 = wid * 16 + srow;       // 0..127
    const int r1 = 128 + r0;
    const unsigned short* aSrc0 = A  + (size_t)(m0 + r0) * K + (schk ^ (r0 & 3)) * 8;
    const unsigned short* aSrc1 = A  + (size_t)(m0 + r1) * K + (schk ^ (r1 & 3)) * 8;
    const unsigned short* bSrc  = Bw + (size_t)(nloc + r0) * K + (schk ^ (r0 & 3)) * 8;

    // fragment read offsets (elements); chunk swizzle ^(row&3) is mi/ni-independent
    const int fr = lane & 15, fg = lane >> 4;
    const int wm = wid >> 1, wn = wid & 1;
    const int ar = wm * 64 + fr;
    const int br = wn * 64 + fr;
    const int aoff = ar * BK + (fg ^ (ar & 3)) * 8;
    const int boff = br * BK + (fg ^ (br & 3)) * 8;

    f32x4 acc[4][4] = {};

#define STAGE(BUF, KOFF)                                                       \
    gload_lds16(aSrc0 + (KOFF), &As[BUF][(wid * 16) * BK]);                    \
    gload_lds16(aSrc1 + (KOFF), &As[BUF][(128 + wid * 16) * BK]);              \
    gload_lds16(bSrc + (KOFF), &Bs[BUF][(wid * 16) * BK]);

#define GBODY(T, BUF)                                                          \
    {                                                                          \
        if ((T) + 1 < NTILES) {                                                \
            asm volatile("s_waitcnt vmcnt(3)" ::: "memory");                   \
        } else {                                                               \
            asm volatile("s_waitcnt vmcnt(0)" ::: "memory");                   \
        }                                                                      \
        __builtin_amdgcn_s_barrier();                                          \
        asm volatile("" ::: "memory");                                         \
        short8 af[4], bf[4];                                                   \
        _Pragma("unroll")                                                      \
        for (int mi = 0; mi < 4; ++mi)                                         \
            af[mi] = *(const short8*)&As[BUF][aoff + mi * (16 * BK)];          \
        _Pragma("unroll")                                                      \
        for (int ni = 0; ni < 4; ++ni)                                         \
            bf[ni] = *(const short8*)&Bs[BUF][boff + ni * (16 * BK)];          \
        __builtin_amdgcn_s_setprio(1);                                         \
        _Pragma("unroll")                                                      \
        for (int mi = 0; mi < 4; ++mi)                                         \
            _Pragma("unroll")                                                  \
            for (int ni = 0; ni < 4; ++ni)                                     \
                acc[mi][ni] = __builtin_amdgcn_mfma_f32_16x16x32_bf16(         \
                    af[mi], bf[ni], acc[mi][ni], 0, 0, 0);                     \
        __builtin_amdgcn_s_setprio(0);                                         \
        asm volatile("s_waitcnt lgkmcnt(0)" ::: "memory");                     \
        __builtin_amdgcn_s_barrier();                                          \
        asm volatile("" ::: "memory");                                         \
        if ((T) + 2 < NTILES) { STAGE(BUF, ((T) + 2) * BK) }                   \
    }

    // prologue: tiles 0,1 in flight
    STAGE(0, 0)
    STAGE(1, BK)

    for (int t = 0; t < NTILES; t += 2) {
        GBODY(t, 0)
        GBODY(t + 1, 1)
    }
#undef GBODY
#undef STAGE

    // ---------------- epilogue ----------------
    if constexpr (MODE == 0) {
        const int nsel = n0 >> 11;
        if (nsel == 2) {
            // V^T: [D_MODEL][MROWS], packed 4-row stores
#pragma unroll
            for (int mi = 0; mi < 4; ++mi)
#pragma unroll
                for (int ni = 0; ni < 4; ++ni) {
                    const int col = nloc + wn * 64 + ni * 16 + fr;
                    const int row0 = m0 + wm * 64 + mi * 16 + fg * 4;
                    const float bv = bias[col];
                    ushort4 o4;
                    o4.x = f2bf(acc[mi][ni][0] + bv);
                    o4.y = f2bf(acc[mi][ni][1] + bv);
                    o4.z = f2bf(acc[mi][ni][2] + bv);
                    o4.w = f2bf(acc[mi][ni][3] + bv);
                    *(ushort4*)&O2[(size_t)col * MROWS + row0] = o4;
                }
        } else {
            unsigned short* Co = nsel ? O1 : O0;
#pragma unroll
            for (int mi = 0; mi < 4; ++mi)
#pragma unroll
                for (int ni = 0; ni < 4; ++ni) {
                    const int col = nloc + wn * 64 + ni * 16 + fr;
                    const float bv = bias[col];
#pragma unroll
                    for (int r = 0; r < 4; ++r) {
                        const int row = m0 + wm * 64 + mi * 16 + fg * 4 + r;
                        Co[(size_t)row * D_MODEL + col] = f2bf(acc[mi][ni][r] + bv);
                    }
                }
        }
    } else {
#pragma unroll
        for (int mi = 0; mi < 4; ++mi)
#pragma unroll
            for (int ni = 0; ni < 4; ++ni) {
                const int col = nloc + wn * 64 + ni * 16 + fr;
                const float bv = bias[col];
#pragma unroll
                for (int r = 0; r < 4; ++r) {
                    const int row = m0 + wm * 64 + mi * 16 + fg * 4 + r;
                    OF[(size_t)row * D_MODEL + col] = acc[mi][ni][r] + bv;
                }
            }
    }
}

// ---------------- flash attention v3 (unchanged from round 3) ----------------
__global__ __launch_bounds__(256, 2)
void flash_attn3(const unsigned short* __restrict__ Q, const unsigned short* __restrict__ Kg,
                 const unsigned short* __restrict__ VT, unsigned short* __restrict__ O) {
    constexpr int KVB = 64;
    constexpr int NT = SEQ / KVB;
    __shared__ unsigned short Ks[2 * KVB * DH];
    __shared__ unsigned short Vs[2 * DH * KVB];

    const int tid  = threadIdx.x;
    const int lane = tid & 63;
    const int wid  = tid >> 6;
    const int l31  = lane & 31;
    const int hi   = lane >> 5;

    const int qt = blockIdx.x & 15;
    const int bh = blockIdx.x >> 4;
    const int b = bh >> 4, h = bh & 15;
    const int qrow = qt * 128 + wid * 32 + l31;

    const unsigned short* Qp = Q + ((size_t)b * SEQ + qrow) * D_MODEL + h * DH;
    const unsigned short* Kp = Kg + (size_t)b * SEQ * D_MODEL + h * DH;
    const unsigned short* Vp = VT + (size_t)(h * DH) * MROWS + (size_t)b * SEQ;

    short8 qf[8];
#pragma unroll
    for (int kk = 0; kk < 8; ++kk)
        qf[kk] = *(const short8*)(Qp + kk * 16 + hi * 8);

    f32x16 acc[4] = {};
    float m_run = -1e30f, l_run = 0.f;
    const float Cc = 0.088388347648318447f * 1.4426950408889634f;
    const float THR = 8.0f / Cc;

    int co[8];
#pragma unroll
    for (int kk = 0; kk < 8; ++kk) co[kk] = ((kk * 2 + hi) ^ (l31 & 7)) * 8;

    int kroff[4], vroff[4];
#pragma unroll
    for (int q = 0; q < 4; ++q) {
        const int row_l = wid * 16 + q * 4 + (lane >> 4);
        kroff[q] = row_l * D_MODEL + ((lane & 15) ^ (row_l & 7)) * 8;
        const int d_l = wid * 32 + q * 8 + (lane >> 3);
        vroff[q] = d_l * MROWS + ((lane & 7) ^ (d_l & 7)) * 8;
    }
    unsigned short* KsW = Ks + (wid * 16) * DH;
    unsigned short* VsW = Vs + (wid * 32) * KVB;

#pragma unroll
    for (int q = 0; q < 4; ++q) {
        gload_lds16(Kp + kroff[q], KsW + q * 4 * DH);
        gload_lds16(Vp + vroff[q], VsW + q * 8 * KVB);
    }
    __syncthreads();

    for (int t = 0; t < NT; ++t) {
        const int cur = t & 1;
        if (t + 1 < NT) {
            const unsigned short* Kt = Kp + (size_t)((t + 1) * KVB) * D_MODEL;
            const unsigned short* Vt = Vp + (t + 1) * KVB;
            unsigned short* kd = KsW + (cur ^ 1) * (KVB * DH);
            unsigned short* vd = VsW + (cur ^ 1) * (DH * KVB);
#pragma unroll
            for (int q = 0; q < 4; ++q) {
                gload_lds16(Kt + kroff[q], kd + q * 4 * DH);
                gload_lds16(Vt + vroff[q], vd + q * 8 * KVB);
            }
        }
        const unsigned short* Kc = Ks + cur * (KVB * DH);
        const unsigned short* Vc = Vs + cur * (DH * KVB);

        f32x16 st0 = {}, st1 = {};
        __builtin_amdgcn_s_setprio(1);
#pragma unroll
        for (int kk = 0; kk < 8; ++kk) {
            const short8 kf0 = *(const short8*)&Kc[l31 * DH + co[kk]];
            const short8 kf1 = *(const short8*)&Kc[(32 + l31) * DH + co[kk]];
            st0 = __builtin_amdgcn_mfma_f32_32x32x16_bf16(kf0, qf[kk], st0, 0, 0, 0);
            st1 = __builtin_amdgcn_mfma_f32_32x32x16_bf16(kf1, qf[kk], st1, 0, 0, 0);
        }
        __builtin_amdgcn_s_setprio(0);

        float lm = -1e30f;
#pragma unroll
        for (int r = 0; r < 16; ++r) lm = fmaxf(lm, fmaxf(st0[r], st1[r]));
        {
            unsigned int a = __builtin_bit_cast(unsigned int, lm), bb = a;
            swap32(a, bb);
            lm = fmaxf(lm, __builtin_bit_cast(float, hi ? a : bb));
        }
        if (__any(lm > m_run + THR)) {
            const float mn = fmaxf(m_run, lm);
            const float sf = __builtin_amdgcn_exp2f((m_run - mn) * Cc);
            m_run = mn;
            l_run *= sf;
#pragma unroll
            for (int db = 0; db < 4; ++db)
#pragma unroll
                for (int r = 0; r < 16; ++r) acc[db][r] *= sf;
        }
        const float mc = m_run * Cc;
        float p0[16], p1[16];
        float ps = 0.f;
#pragma unroll
        for (int r = 0; r < 16; ++r) {
            p0[r] = __builtin_amdgcn_exp2f(__builtin_fmaf(st0[r], Cc, -mc));
            p1[r] = __builtin_amdgcn_exp2f(__builtin_fmaf(st1[r], Cc, -mc));
            ps += p0[r] + p1[r];
        }
        {
            unsigned int a = __builtin_bit_cast(unsigned int, ps), bb = a;
            swap32(a, bb);
            ps += __builtin_bit_cast(float, hi ? a : bb);
        }
        l_run += ps;

        unsigned int W0[8], W1[8];
#pragma unroll
        for (int tt = 0; tt < 8; ++tt) {
            W0[tt] = cvt_pk_bf16(p0[2 * tt], p0[2 * tt + 1]);
            W1[tt] = cvt_pk_bf16(p1[2 * tt], p1[2 * tt + 1]);
        }
        swap32(W0[0], W0[2]); swap32(W0[1], W0[3]);
        swap32(W0[4], W0[6]); swap32(W0[5], W0[7]);
        swap32(W1[0], W1[2]); swap32(W1[1], W1[3]);
        swap32(W1[4], W1[6]); swap32(W1[5], W1[7]);
        short8 pf[4];
        {
            uint4 f;
            f.x = W0[0]; f.y = W0[1]; f.z = W0[2]; f.w = W0[3];
            pf[0] = __builtin_bit_cast(short8, f);
            f.x = W0[4]; f.y = W0[5]; f.z = W0[6]; f.w = W0[7];
            pf[1] = __builtin_bit_cast(short8, f);
            f.x = W1[0]; f.y = W1[1]; f.z = W1[2]; f.w = W1[3];
            pf[2] = __builtin_bit_cast(short8, f);
            f.x = W1[4]; f.y = W1[5]; f.z = W1[6]; f.w = W1[7];
            pf[3] = __builtin_bit_cast(short8, f);
        }

        __builtin_amdgcn_s_setprio(1);
#pragma unroll
        for (int db = 0; db < 4; ++db) {
#pragma unroll
            for (int kk16 = 0; kk16 < 4; ++kk16) {
                const short8 vf = *(const short8*)&Vc[(db * 32 + l31) * KVB + co[kk16]];
                acc[db] = __builtin_amdgcn_mfma_f32_32x32x16_bf16(vf, pf[kk16], acc[db], 0, 0, 0);
            }
        }
        __builtin_amdgcn_s_setprio(0);
        __syncthreads();
    }

    const float inv_l = 1.0f / l_run;
    unsigned short* Op = O + ((size_t)b * SEQ + qrow) * D_MODEL + h * DH;
#pragma unroll
    for (int db = 0; db < 4; ++db)
#pragma unroll
        for (int g = 0; g < 4; ++g) {
            ushort4 o4;
            o4.x = f2bf(acc[db][4 * g + 0] * inv_l);
            o4.y = f2bf(acc[db][4 * g + 1] * inv_l);
            o4.z = f2bf(acc[db][4 * g + 2] * inv_l);
            o4.w = f2bf(acc[db][4 * g + 3] * inv_l);
            *(ushort4*)(Op + db * 32 + g * 8 + hi * 4) = o4;
        }
}

// ---------------- host launch ----------------
extern "C" void kernel_launch(void* const* d_in, const int* in_sizes, int n_in,
                              void* d_out, int out_size, void* d_ws, size_t ws_size,
                              hipStream_t stream) {
    (void)in_sizes; (void)n_in; (void)out_size; (void)ws_size;
    const float* x  = (const float*)d_in[0];
    const float* wq = (const float*)d_in[1];
    const float* bq = (const float*)d_in[2];
    const float* wk = (const float*)d_in[3];
    const float* bk = (const float*)d_in[4];
    const float* wv = (const float*)d_in[5];
    const float* bv = (const float*)d_in[6];
    const float* wo = (const float*)d_in[7];
    const float* bo = (const float*)d_in[8];
    float* out = (float*)d_out;

    unsigned short* ws = (unsigned short*)d_ws;
    const size_t NX = (size_t)MROWS * D_MODEL;
    const size_t NW = (size_t)D_MODEL * D_MODEL;
    unsigned short* xb  = ws;
    unsigned short* wqb = xb + NX;
    unsigned short* wkb = wqb + NW;
    unsigned short* wvb = wkb + NW;
    unsigned short* wob = wvb + NW;
    unsigned short* Qb  = wob + NW;
    unsigned short* Kb  = Qb + NX;
    unsigned short* VTb = Kb + NX;   // V^T: [D_MODEL][MROWS]
    unsigned short* Ab  = VTb + NX;

    cvt_kernel<<<(unsigned)(NX / 1024), 256, 0, stream>>>(x, xb, (int)(NX / 4));
    cvt4_kernel<<<(unsigned)(4 * NW / 1024), 256, 0, stream>>>(wq, wk, wv, wo, wqb);

    gemm8<0><<<768, 512, 0, stream>>>(xb, wqb, wkb, wvb, bq, bk, bv,
                                      Qb, Kb, VTb, nullptr);

    flash_attn3<<<512, 256, 0, stream>>>(Qb, Kb, VTb, Ab);

    gemm8<1><<<256, 512, 0, stream>>>(Ab, wob, nullptr, nullptr, bo, nullptr, nullptr,
                                      nullptr, nullptr, nullptr, out);
}

// Round 5
// 263.655 us; speedup vs baseline: 1.1292x; 1.1292x over previous
//
#include <hip/hip_runtime.h>
#include <cstdint>
#include <cstddef>

#define D_MODEL 2048
#define SEQ 2048
#define BATCH 2
#define HEADS 16
#define DH 128
#define MROWS (BATCH * SEQ) /* 4096 */

typedef __attribute__((ext_vector_type(8))) short short8;
typedef __attribute__((ext_vector_type(4))) float f32x4;
typedef __attribute__((ext_vector_type(16))) float f32x16;
typedef __attribute__((ext_vector_type(2))) unsigned int uint2e;

__device__ __forceinline__ unsigned short f2bf(float f) {
    unsigned int u = __builtin_bit_cast(unsigned int, f);
    u += 0x7fffu + ((u >> 16) & 1u);   // round-to-nearest-even
    return (unsigned short)(u >> 16);
}

__device__ __forceinline__ unsigned int cvt_pk_bf16(float lo, float hi) {
    unsigned int w;
    asm("v_cvt_pk_bf16_f32 %0, %1, %2" : "=v"(w) : "v"(lo), "v"(hi));
    return w;
}

__device__ __forceinline__ void swap32(unsigned int& x, unsigned int& y) {
#if __has_builtin(__builtin_amdgcn_permlane32_swap)
    uint2e r = __builtin_amdgcn_permlane32_swap(x, y, false, false);
    x = r[0]; y = r[1];
#else
    const int hi = (threadIdx.x >> 5) & 1;
    const unsigned int gx = (unsigned int)__shfl_xor((int)x, 32);
    const unsigned int gy = (unsigned int)__shfl_xor((int)y, 32);
    const unsigned int nx = hi ? gy : x;
    const unsigned int ny = hi ? y : gx;
    x = nx; y = ny;
#endif
}

__device__ __forceinline__ void gload_lds16(const unsigned short* g, unsigned short* l) {
    __builtin_amdgcn_global_load_lds(
        (const __attribute__((address_space(1))) void*)g,
        (__attribute__((address_space(3))) void*)l, 16, 0, 0);
}

// ---------------- fp32 -> bf16 conversion ----------------
__global__ __launch_bounds__(256) void cvt_kernel(const float* __restrict__ in,
                                                  unsigned short* __restrict__ out, int n4) {
    int i = blockIdx.x * 256 + threadIdx.x;
    if (i < n4) {
        const float4 v = reinterpret_cast<const float4*>(in)[i];
        ushort4 o;
        o.x = f2bf(v.x); o.y = f2bf(v.y); o.z = f2bf(v.z); o.w = f2bf(v.w);
        reinterpret_cast<ushort4*>(out)[i] = o;
    }
}

__global__ __launch_bounds__(256) void cvt4_kernel(const float* __restrict__ w0,
                                                   const float* __restrict__ w1,
                                                   const float* __restrict__ w2,
                                                   const float* __restrict__ w3,
                                                   unsigned short* __restrict__ out) {
    const int per = (D_MODEL * D_MODEL) / 4;
    int i = blockIdx.x * 256 + threadIdx.x;
    const int sel = i / per;
    const int off = i - sel * per;
    const float* s = sel == 0 ? w0 : sel == 1 ? w1 : sel == 2 ? w2 : w3;
    const float4 v = reinterpret_cast<const float4*>(s)[off];
    ushort4 o;
    o.x = f2bf(v.x); o.y = f2bf(v.y); o.z = f2bf(v.z); o.w = f2bf(v.w);
    reinterpret_cast<ushort4*>(out)[i] = o;
}

// ---------------- deep-pipelined GEMM: C = A * W^T + bias ----------------
// BM=256, BN=128, BK=64; 8 waves (4M x 2N, 64x64/wave); TRIPLE-buffered LDS
// (144KB) so the tile-boundary wait is counted vmcnt(6), never a drain.
// Two 16-MFMA phases per K-tile: {ds_read frags || stage 3 loads of tile t+2
// -> barrier -> lgkmcnt(0)+sched_barrier -> setprio(1) MFMA x16 setprio(0)
// -> barrier}. BK=64 gives the 8-chunk XOR swizzle (2-way free on b128 reads).
// MODE 0: fused QKV (N=6144 over 3 weights; V written transposed).
// MODE 1: f32 row-major out (attention output projection).
template <int MODE>
__global__ __launch_bounds__(512, 2)
void gemmT(const unsigned short* __restrict__ A,
           const unsigned short* __restrict__ W0,
           const unsigned short* __restrict__ W1,
           const unsigned short* __restrict__ W2,
           const float* __restrict__ b0f,
           const float* __restrict__ b1f,
           const float* __restrict__ b2f,
           unsigned short* __restrict__ O0,
           unsigned short* __restrict__ O1,
           unsigned short* __restrict__ O2,
           float* __restrict__ OF) {
    constexpr int BM = 256, BN = 128, BK = 64;
    constexpr int K = D_MODEL;
    constexpr int NTILES = K / BK;                         // 32
    constexpr int NT_N = (MODE == 0 ? 48 : 16);
    constexpr int NWG = (MROWS / BM) * NT_N;               // 768 / 256
    constexpr int ASZ = BM * BK;                           // 16384
    constexpr int BSZ = BN * BK;                           // 8192
    __shared__ unsigned short As[3][ASZ];                  // 96KB
    __shared__ unsigned short Bs[3][BSZ];                  // 48KB

    const int tid  = threadIdx.x;
    const int lane = tid & 63;
    const int wid  = tid >> 6;

    // T1 bijective XCD swizzle (NWG % 8 == 0); nt-fastest (B panel L2 reuse)
    const int wk = (blockIdx.x & 7) * (NWG >> 3) + (blockIdx.x >> 3);
    const int nt = wk % NT_N;
    const int mt = wk / NT_N;
    const int m0 = mt * BM;
    const int n0 = nt * BN;

    const unsigned short* Bw;
    const float* bias;
    int nloc;
    if constexpr (MODE == 0) {
        const int nsel = n0 >> 11;
        nloc = n0 & 2047;
        Bw = nsel == 0 ? W0 : (nsel == 1 ? W1 : W2);
        bias = nsel == 0 ? b0f : (nsel == 1 ? b1f : b2f);
    } else {
        Bw = W0; bias = b0f; nloc = n0;
    }

    // ---- staging geometry: 512 threads cover 64 rows x 8 chunks per load ----
    const int srow = tid >> 3;            // 0..63
    const int sch  = tid & 7;
    const int ssw  = (sch ^ (srow & 7)) * 8;   // inverse-swizzled source chunk
    const int sd   = srow * 64 + sch * 8;      // linear LDS dest (elements)
    const unsigned short* aS[4];
#pragma unroll
    for (int j = 0; j < 4; ++j) aS[j] = A + (size_t)(m0 + j * 64 + srow) * K + ssw;
    const unsigned short* bS[2];
#pragma unroll
    for (int j = 0; j < 2; ++j) bS[j] = Bw + (size_t)(nloc + j * 64 + srow) * K + ssw;

    // ---- fragment geometry ----
    const int fr = lane & 15, fg = lane >> 4;
    const int wm = wid >> 1, wn = wid & 1;     // 4M x 2N waves
    int aoff[4][2], boff[4][2];
#pragma unroll
    for (int mi = 0; mi < 4; ++mi)
#pragma unroll
        for (int ks = 0; ks < 2; ++ks) {
            aoff[mi][ks] = (wm * 64 + mi * 16 + fr) * BK + ((ks * 4 + fg) ^ (fr & 7)) * 8;
            boff[mi][ks] = (wn * 64 + mi * 16 + fr) * BK + ((ks * 4 + fg) ^ (fr & 7)) * 8;
        }

    f32x4 acc[4][4] = {};

    unsigned short *pA0 = As[0], *pA1 = As[1], *pA2 = As[2];
    unsigned short *pB0 = Bs[0], *pB1 = Bs[1], *pB2 = Bs[2];

#define STG_A(P, T, J) gload_lds16(aS[J] + (T) * BK, (P) + (J) * 4096 + sd)
#define STG_B(P, T, J) gload_lds16(bS[J] + (T) * BK, (P) + (J) * 4096 + sd)

    // prologue: tiles 0 and 1 fully staged (6 loads each)
    STG_A(pA0, 0, 0); STG_A(pA0, 0, 1); STG_A(pA0, 0, 2); STG_A(pA0, 0, 3);
    STG_B(pB0, 0, 0); STG_B(pB0, 0, 1);
    STG_A(pA1, 1, 0); STG_A(pA1, 1, 1); STG_A(pA1, 1, 2); STG_A(pA1, 1, 3);
    STG_B(pB1, 1, 0); STG_B(pB1, 1, 1);
    asm volatile("s_waitcnt vmcnt(6)" ::: "memory");   // tile 0 landed
    __builtin_amdgcn_s_barrier();

    for (int t = 0; t < NTILES; ++t) {
        const bool more = (t + 2 < NTILES);
        // ================= phase 0 (n-frags 0,1) =================
        short8 aF[4][2], bF0[2][2];
#pragma unroll
        for (int mi = 0; mi < 4; ++mi)
#pragma unroll
            for (int ks = 0; ks < 2; ++ks)
                aF[mi][ks] = *(const short8*)&pA0[aoff[mi][ks]];
#pragma unroll
        for (int ni = 0; ni < 2; ++ni)
#pragma unroll
            for (int ks = 0; ks < 2; ++ks)
                bF0[ni][ks] = *(const short8*)&pB0[boff[ni][ks]];
        if (more) { STG_A(pA2, t + 2, 0); STG_A(pA2, t + 2, 1); STG_B(pB2, t + 2, 0); }
        __builtin_amdgcn_s_barrier();
        asm volatile("s_waitcnt lgkmcnt(0)" ::: "memory");
        __builtin_amdgcn_sched_barrier(0);
        __builtin_amdgcn_s_setprio(1);
#pragma unroll
        for (int ks = 0; ks < 2; ++ks)
#pragma unroll
            for (int mi = 0; mi < 4; ++mi)
#pragma unroll
                for (int ni = 0; ni < 2; ++ni)
                    acc[mi][ni] = __builtin_amdgcn_mfma_f32_16x16x32_bf16(
                        aF[mi][ks], bF0[ni][ks], acc[mi][ni], 0, 0, 0);
        __builtin_amdgcn_s_setprio(0);
        __builtin_amdgcn_s_barrier();
        // ================= phase 1 (n-frags 2,3) =================
        short8 bF1[2][2];
#pragma unroll
        for (int ni = 0; ni < 2; ++ni)
#pragma unroll
            for (int ks = 0; ks < 2; ++ks)
                bF1[ni][ks] = *(const short8*)&pB0[boff[2 + ni][ks]];
        if (more) { STG_A(pA2, t + 2, 2); STG_A(pA2, t + 2, 3); STG_B(pB2, t + 2, 1); }
        __builtin_amdgcn_s_barrier();
        asm volatile("s_waitcnt lgkmcnt(0)" ::: "memory");
        __builtin_amdgcn_sched_barrier(0);
        __builtin_amdgcn_s_setprio(1);
#pragma unroll
        for (int ks = 0; ks < 2; ++ks)
#pragma unroll
            for (int mi = 0; mi < 4; ++mi)
#pragma unroll
                for (int ni = 0; ni < 2; ++ni)
                    acc[mi][2 + ni] = __builtin_amdgcn_mfma_f32_16x16x32_bf16(
                        aF[mi][ks], bF1[ni][ks], acc[mi][2 + ni], 0, 0, 0);
        __builtin_amdgcn_s_setprio(0);
        // tile boundary: counted wait (next tile's 6 loads landed; t+2's stay in flight)
        if (more) asm volatile("s_waitcnt vmcnt(6)" ::: "memory");
        else      asm volatile("s_waitcnt vmcnt(0)" ::: "memory");
        __builtin_amdgcn_s_barrier();
        // rotate triple buffers
        unsigned short* tA = pA0; pA0 = pA1; pA1 = pA2; pA2 = tA;
        unsigned short* tB = pB0; pB0 = pB1; pB1 = pB2; pB2 = tB;
    }
#undef STG_A
#undef STG_B

    // ---------------- epilogue ----------------
    if constexpr (MODE == 0) {
        const int nsel = n0 >> 11;
        if (nsel == 2) {
            // V^T: [D_MODEL][MROWS], packed 4-row stores
#pragma unroll
            for (int mi = 0; mi < 4; ++mi)
#pragma unroll
                for (int ni = 0; ni < 4; ++ni) {
                    const int col = nloc + wn * 64 + ni * 16 + fr;
                    const int row0 = m0 + wm * 64 + mi * 16 + fg * 4;
                    const float bv = bias[col];
                    ushort4 o4;
                    o4.x = f2bf(acc[mi][ni][0] + bv);
                    o4.y = f2bf(acc[mi][ni][1] + bv);
                    o4.z = f2bf(acc[mi][ni][2] + bv);
                    o4.w = f2bf(acc[mi][ni][3] + bv);
                    *(ushort4*)&O2[(size_t)col * MROWS + row0] = o4;
                }
        } else {
            unsigned short* Co = nsel ? O1 : O0;
#pragma unroll
            for (int mi = 0; mi < 4; ++mi)
#pragma unroll
                for (int ni = 0; ni < 4; ++ni) {
                    const int col = nloc + wn * 64 + ni * 16 + fr;
                    const float bv = bias[col];
#pragma unroll
                    for (int r = 0; r < 4; ++r) {
                        const int row = m0 + wm * 64 + mi * 16 + fg * 4 + r;
                        Co[(size_t)row * D_MODEL + col] = f2bf(acc[mi][ni][r] + bv);
                    }
                }
        }
    } else {
#pragma unroll
        for (int mi = 0; mi < 4; ++mi)
#pragma unroll
            for (int ni = 0; ni < 4; ++ni) {
                const int col = nloc + wn * 64 + ni * 16 + fr;
                const float bv = bias[col];
#pragma unroll
                for (int r = 0; r < 4; ++r) {
                    const int row = m0 + wm * 64 + mi * 16 + fg * 4 + r;
                    OF[(size_t)row * D_MODEL + col] = acc[mi][ni][r] + bv;
                }
            }
    }
}

// ---------------- flash attention v3 (unchanged) ----------------
__global__ __launch_bounds__(256, 2)
void flash_attn3(const unsigned short* __restrict__ Q, const unsigned short* __restrict__ Kg,
                 const unsigned short* __restrict__ VT, unsigned short* __restrict__ O) {
    constexpr int KVB = 64;
    constexpr int NT = SEQ / KVB;
    __shared__ unsigned short Ks[2 * KVB * DH];
    __shared__ unsigned short Vs[2 * DH * KVB];

    const int tid  = threadIdx.x;
    const int lane = tid & 63;
    const int wid  = tid >> 6;
    const int l31  = lane & 31;
    const int hi   = lane >> 5;

    const int qt = blockIdx.x & 15;
    const int bh = blockIdx.x >> 4;
    const int b = bh >> 4, h = bh & 15;
    const int qrow = qt * 128 + wid * 32 + l31;

    const unsigned short* Qp = Q + ((size_t)b * SEQ + qrow) * D_MODEL + h * DH;
    const unsigned short* Kp = Kg + (size_t)b * SEQ * D_MODEL + h * DH;
    const unsigned short* Vp = VT + (size_t)(h * DH) * MROWS + (size_t)b * SEQ;

    short8 qf[8];
#pragma unroll
    for (int kk = 0; kk < 8; ++kk)
        qf[kk] = *(const short8*)(Qp + kk * 16 + hi * 8);

    f32x16 acc[4] = {};
    float m_run = -1e30f, l_run = 0.f;
    const float Cc = 0.088388347648318447f * 1.4426950408889634f;
    const float THR = 8.0f / Cc;

    int co[8];
#pragma unroll
    for (int kk = 0; kk < 8; ++kk) co[kk] = ((kk * 2 + hi) ^ (l31 & 7)) * 8;

    int kroff[4], vroff[4];
#pragma unroll
    for (int q = 0; q < 4; ++q) {
        const int row_l = wid * 16 + q * 4 + (lane >> 4);
        kroff[q] = row_l * D_MODEL + ((lane & 15) ^ (row_l & 7)) * 8;
        const int d_l = wid * 32 + q * 8 + (lane >> 3);
        vroff[q] = d_l * MROWS + ((lane & 7) ^ (d_l & 7)) * 8;
    }
    unsigned short* KsW = Ks + (wid * 16) * DH;
    unsigned short* VsW = Vs + (wid * 32) * KVB;

#pragma unroll
    for (int q = 0; q < 4; ++q) {
        gload_lds16(Kp + kroff[q], KsW + q * 4 * DH);
        gload_lds16(Vp + vroff[q], VsW + q * 8 * KVB);
    }
    __syncthreads();

    for (int t = 0; t < NT; ++t) {
        const int cur = t & 1;
        if (t + 1 < NT) {
            const unsigned short* Kt = Kp + (size_t)((t + 1) * KVB) * D_MODEL;
            const unsigned short* Vt = Vp + (t + 1) * KVB;
            unsigned short* kd = KsW + (cur ^ 1) * (KVB * DH);
            unsigned short* vd = VsW + (cur ^ 1) * (DH * KVB);
#pragma unroll
            for (int q = 0; q < 4; ++q) {
                gload_lds16(Kt + kroff[q], kd + q * 4 * DH);
                gload_lds16(Vt + vroff[q], vd + q * 8 * KVB);
            }
        }
        const unsigned short* Kc = Ks + cur * (KVB * DH);
        const unsigned short* Vc = Vs + cur * (DH * KVB);

        f32x16 st0 = {}, st1 = {};
        __builtin_amdgcn_s_setprio(1);
#pragma unroll
        for (int kk = 0; kk < 8; ++kk) {
            const short8 kf0 = *(const short8*)&Kc[l31 * DH + co[kk]];
            const short8 kf1 = *(const short8*)&Kc[(32 + l31) * DH + co[kk]];
            st0 = __builtin_amdgcn_mfma_f32_32x32x16_bf16(kf0, qf[kk], st0, 0, 0, 0);
            st1 = __builtin_amdgcn_mfma_f32_32x32x16_bf16(kf1, qf[kk], st1, 0, 0, 0);
        }
        __builtin_amdgcn_s_setprio(0);

        float lm = -1e30f;
#pragma unroll
        for (int r = 0; r < 16; ++r) lm = fmaxf(lm, fmaxf(st0[r], st1[r]));
        {
            unsigned int a = __builtin_bit_cast(unsigned int, lm), bb = a;
            swap32(a, bb);
            lm = fmaxf(lm, __builtin_bit_cast(float, hi ? a : bb));
        }
        if (__any(lm > m_run + THR)) {
            const float mn = fmaxf(m_run, lm);
            const float sf = __builtin_amdgcn_exp2f((m_run - mn) * Cc);
            m_run = mn;
            l_run *= sf;
#pragma unroll
            for (int db = 0; db < 4; ++db)
#pragma unroll
                for (int r = 0; r < 16; ++r) acc[db][r] *= sf;
        }
        const float mc = m_run * Cc;
        float p0[16], p1[16];
        float ps = 0.f;
#pragma unroll
        for (int r = 0; r < 16; ++r) {
            p0[r] = __builtin_amdgcn_exp2f(__builtin_fmaf(st0[r], Cc, -mc));
            p1[r] = __builtin_amdgcn_exp2f(__builtin_fmaf(st1[r], Cc, -mc));
            ps += p0[r] + p1[r];
        }
        {
            unsigned int a = __builtin_bit_cast(unsigned int, ps), bb = a;
            swap32(a, bb);
            ps += __builtin_bit_cast(float, hi ? a : bb);
        }
        l_run += ps;

        unsigned int W0[8], W1[8];
#pragma unroll
        for (int tt = 0; tt < 8; ++tt) {
            W0[tt] = cvt_pk_bf16(p0[2 * tt], p0[2 * tt + 1]);
            W1[tt] = cvt_pk_bf16(p1[2 * tt], p1[2 * tt + 1]);
        }
        swap32(W0[0], W0[2]); swap32(W0[1], W0[3]);
        swap32(W0[4], W0[6]); swap32(W0[5], W0[7]);
        swap32(W1[0], W1[2]); swap32(W1[1], W1[3]);
        swap32(W1[4], W1[6]); swap32(W1[5], W1[7]);
        short8 pf[4];
        {
            uint4 f;
            f.x = W0[0]; f.y = W0[1]; f.z = W0[2]; f.w = W0[3];
            pf[0] = __builtin_bit_cast(short8, f);
            f.x = W0[4]; f.y = W0[5]; f.z = W0[6]; f.w = W0[7];
            pf[1] = __builtin_bit_cast(short8, f);
            f.x = W1[0]; f.y = W1[1]; f.z = W1[2]; f.w = W1[3];
            pf[2] = __builtin_bit_cast(short8, f);
            f.x = W1[4]; f.y = W1[5]; f.z = W1[6]; f.w = W1[7];
            pf[3] = __builtin_bit_cast(short8, f);
        }

        __builtin_amdgcn_s_setprio(1);
#pragma unroll
        for (int db = 0; db < 4; ++db) {
#pragma unroll
            for (int kk16 = 0; kk16 < 4; ++kk16) {
                const short8 vf = *(const short8*)&Vc[(db * 32 + l31) * KVB + co[kk16]];
                acc[db] = __builtin_amdgcn_mfma_f32_32x32x16_bf16(vf, pf[kk16], acc[db], 0, 0, 0);
            }
        }
        __builtin_amdgcn_s_setprio(0);
        __syncthreads();
    }

    const float inv_l = 1.0f / l_run;
    unsigned short* Op = O + ((size_t)b * SEQ + qrow) * D_MODEL + h * DH;
#pragma unroll
    for (int db = 0; db < 4; ++db)
#pragma unroll
        for (int g = 0; g < 4; ++g) {
            ushort4 o4;
            o4.x = f2bf(acc[db][4 * g + 0] * inv_l);
            o4.y = f2bf(acc[db][4 * g + 1] * inv_l);
            o4.z = f2bf(acc[db][4 * g + 2] * inv_l);
            o4.w = f2bf(acc[db][4 * g + 3] * inv_l);
            *(ushort4*)(Op + db * 32 + g * 8 + hi * 4) = o4;
        }
}

// ---------------- host launch ----------------
extern "C" void kernel_launch(void* const* d_in, const int* in_sizes, int n_in,
                              void* d_out, int out_size, void* d_ws, size_t ws_size,
                              hipStream_t stream) {
    (void)in_sizes; (void)n_in; (void)out_size; (void)ws_size;
    const float* x  = (const float*)d_in[0];
    const float* wq = (const float*)d_in[1];
    const float* bq = (const float*)d_in[2];
    const float* wk = (const float*)d_in[3];
    const float* bk = (const float*)d_in[4];
    const float* wv = (const float*)d_in[5];
    const float* bv = (const float*)d_in[6];
    const float* wo = (const float*)d_in[7];
    const float* bo = (const float*)d_in[8];
    float* out = (float*)d_out;

    unsigned short* ws = (unsigned short*)d_ws;
    const size_t NX = (size_t)MROWS * D_MODEL;
    const size_t NW = (size_t)D_MODEL * D_MODEL;
    unsigned short* xb  = ws;
    unsigned short* wqb = xb + NX;
    unsigned short* wkb = wqb + NW;
    unsigned short* wvb = wkb + NW;
    unsigned short* wob = wvb + NW;
    unsigned short* Qb  = wob + NW;
    unsigned short* Kb  = Qb + NX;
    unsigned short* VTb = Kb + NX;   // V^T: [D_MODEL][MROWS]
    unsigned short* Ab  = VTb + NX;

    cvt_kernel<<<(unsigned)(NX / 1024), 256, 0, stream>>>(x, xb, (int)(NX / 4));
    cvt4_kernel<<<(unsigned)(4 * NW / 1024), 256, 0, stream>>>(wq, wk, wv, wo, wqb);

    gemmT<0><<<768, 512, 0, stream>>>(xb, wqb, wkb, wvb, bq, bk, bv,
                                      Qb, Kb, VTb, nullptr);

    flash_attn3<<<512, 256, 0, stream>>>(Qb, Kb, VTb, Ab);

    gemmT<1><<<256, 512, 0, stream>>>(Ab, wob, nullptr, nullptr, bo, nullptr, nullptr,
                                      nullptr, nullptr, nullptr, out);
}